// Round 8
// baseline (183.114 us; speedup 1.0000x reference)
//
#include <hip/hip_runtime.h>
#include <cstdint>
#include <cstddef>

typedef __attribute__((ext_vector_type(8))) __bf16   bf16x8;
typedef __attribute__((ext_vector_type(2))) __bf16   bf16x2;
typedef __attribute__((ext_vector_type(4))) float    f32x4;
typedef __attribute__((ext_vector_type(4))) uint32_t u32x4;

#define N_ROWS   1179648   // 8*384*384
#define N_TILES  73728     // N_ROWS/16
#define BLOCKS   2048      // 4 waves -> 8192 waves -> 9 tiles/wave
#define TPW      9
#define SDIM     384
#define VOCAB    5

// LDS map (29184 B): [0,24576) W1|W2'|W3' bf16 permuted+swizzled;
// [24576,26624) Wo'^T padded; [26624,27904) b1|b2'|b3'|ws2|ws3 f32 (320 f32);
// [27904,29184) 4 waves x 320B out-gather
#define WO_OFF   24576
#define BIAS_OFF 26624
#define OUT_OFF  27904

// tanh-form GELU via exp2+rcp: gelu(x) ~= x / (1 + exp2(x*(c1+c2*x^2)))
// |err vs exact| <= ~4e-4 (threshold 7.75e-2)
__device__ __forceinline__ f32x4 gelu4(f32x4 x){
  f32x4 u = x * x;
  f32x4 w = u * (-0.10294456f) + (-2.3021255f);
  f32x4 z = x * w;
  f32x4 e;
  e[0] = __builtin_amdgcn_exp2f(z[0]);
  e[1] = __builtin_amdgcn_exp2f(z[1]);
  e[2] = __builtin_amdgcn_exp2f(z[2]);
  e[3] = __builtin_amdgcn_exp2f(z[3]);
  f32x4 d = e + 1.0f;
  f32x4 r;
  r[0] = __builtin_amdgcn_rcpf(d[0]);
  r[1] = __builtin_amdgcn_rcpf(d[1]);
  r[2] = __builtin_amdgcn_rcpf(d[2]);
  r[3] = __builtin_amdgcn_rcpf(d[3]);
  return x * r;
}

__device__ __forceinline__ bf16x8 mk_bf8(f32x4 a, f32x4 b){
  bf16x8 v;
  v[0]=(__bf16)a[0]; v[1]=(__bf16)a[1]; v[2]=(__bf16)a[2]; v[3]=(__bf16)a[3];
  v[4]=(__bf16)b[0]; v[5]=(__bf16)b[1]; v[6]=(__bf16)b[2]; v[7]=(__bf16)b[3];
  return v;
}

// W-row permutation: global row m -> LDS A-row rho, so acc[mt][r] of lane (h,b)
// is feature 8h + r + 4*(mt&1) + 32*(mt>>1) -> next B frag is pure register repack.
__device__ __forceinline__ int perm_rho(int m){
  return (m & 0x23) | ((m & 4) << 2) | ((m & 0x18) >> 1);
}

__global__ __launch_bounds__(256)   // natural allocation (R7's (256,4) clamp: AGPR shuffles, -35%)
void mlp_kernel(const float* __restrict__ x,
                const float* __restrict__ W1, const float* __restrict__ b1,
                const float* __restrict__ W2, const float* __restrict__ b2,
                const float* __restrict__ W3, const float* __restrict__ b3,
                const float* __restrict__ lng, const float* __restrict__ lnb,
                const float* __restrict__ Wo,  const float* __restrict__ bo,
                float* __restrict__ tmp)
{
  __shared__ __align__(16) uint8_t Wl[29184];

  const int tid = threadIdx.x;

  // ---- stage weights with LN-affine folding ----
  // W1 raw; W2',W3',Wo' have column k scaled by lng[k] (they consume LN outputs).
  {
    int m = tid & 63, g = tid >> 6;
    int rho = perm_rho(m);
    uint8_t* wrow = Wl + rho * 128;
    int swz = (rho & 7) << 4;
    #pragma unroll 1
    for (int idx = g; idx < 96; idx += 4) {   // idx = L*32 + kp
      int L = idx >> 5, kp = idx & 31;
      const float* W = (L == 0) ? W1 : ((L == 1) ? W2 : W3);
      float g0 = (L == 0) ? 1.0f : lng[2 * kp];
      float g1 = (L == 0) ? 1.0f : lng[2 * kp + 1];
      float lo = W[(2 * kp    ) * 64 + m] * g0;
      float hi = W[(2 * kp + 1) * 64 + m] * g1;
      bf16x2 p = { (__bf16)lo, (__bf16)hi };
      *(uint32_t*)(wrow + L * 8192 + ((4 * kp) ^ swz)) = __builtin_bit_cast(uint32_t, p);
    }
    int mm = tid & 15;
    #pragma unroll 1
    for (int kp = tid >> 4; kp < 32; kp += 16) {    // Wo' rows 0..15 (>=5 zero)
      float g0 = lng[2 * kp], g1 = lng[2 * kp + 1];
      float lo = (mm < VOCAB) ? Wo[(2 * kp    ) * VOCAB + mm] * g0 : 0.0f;
      float hi = (mm < VOCAB) ? Wo[(2 * kp + 1) * VOCAB + mm] * g1 : 0.0f;
      bf16x2 p = { (__bf16)lo, (__bf16)hi };
      *(uint32_t*)(Wl + WO_OFF + mm * 128 + ((4 * kp) ^ ((mm & 7) << 4))) =
          __builtin_bit_cast(uint32_t, p);
    }
    // b1 raw; b2' = b2 + W2^T.lnb, ws2 = W2^T.lng; same for W3.
    if (tid < 128) {
      int m2 = tid & 63;
      const float* W = (tid < 64) ? W2 : W3;
      float d = (tid < 64) ? b2[m2] : b3[m2];
      float s = 0.0f;
      #pragma unroll 4
      for (int k = 0; k < 64; ++k) {
        float w = W[k * 64 + m2];
        d = __builtin_fmaf(w, lnb[k], d);
        s = __builtin_fmaf(w, lng[k], s);
      }
      *(float*)(Wl + BIAS_OFF + (64  + tid) * 4) = d;   // b2'|b3' slots [64,192)
      *(float*)(Wl + BIAS_OFF + (192 + tid) * 4) = s;   // ws2|ws3 slots [192,320)
    } else if (tid < 192) {
      *(float*)(Wl + BIAS_OFF + (tid - 128) * 4) = b1[tid - 128];
    }
  }
  __syncthreads();

  const int wav  = tid >> 6, lane = tid & 63;
  const int h    = lane >> 4;
  const int b    = lane & 15;
  const int swzW = (b & 7) << 4;
  const int rowB = b * 128;
  const int kOff = 16 * h;
  const float* biasL = (const float*)(Wl + BIAS_OFF);
  float* myF = (float*)(Wl + OUT_OFF) + wav * 80;

  // bo' = bo + Wo^T.lnb and wso = Wo^T.lng, per-lane (prologue, off hot path)
  f32x4 aoInit, wsoInit;
  #pragma unroll
  for (int r = 0; r < 4; ++r) {
    int v = 4 * h + r;
    aoInit[r]  = (v < VOCAB) ? bo[v] : 0.0f;
    wsoInit[r] = 0.0f;
  }
  #pragma unroll 4
  for (int k = 0; k < 64; ++k) {
    float lb = lnb[k], lg = lng[k];
    #pragma unroll
    for (int r = 0; r < 4; ++r) {
      int v = 4 * h + r;
      if (v < VOCAB) {
        float w = Wo[k * VOCAB + v];
        aoInit[r]  = __builtin_fmaf(lb, w, aoInit[r]);
        wsoInit[r] = __builtin_fmaf(lg, w, wsoInit[r]);
      }
    }
  }

  const int gw = blockIdx.x * 4 + wav;   // 0..8191
  int t = gw * TPW;

  f32x4 xn[4];
  {
    const float* px = x + (size_t)(t * 16 + b) * 64 + 8 * h;
    xn[0] = *(const f32x4*)(px);      xn[1] = *(const f32x4*)(px + 4);
    xn[2] = *(const f32x4*)(px + 32); xn[3] = *(const f32x4*)(px + 36);
  }

  const f32x4 zf = { 0.0f, 0.0f, 0.0f, 0.0f };

  #pragma unroll 1
  for (int i = 0; i < TPW; ++i, ++t) {
    u32x4 bfr[2];
    bfr[0] = __builtin_bit_cast(u32x4, mk_bf8(xn[0], xn[1]));
    bfr[1] = __builtin_bit_cast(u32x4, mk_bf8(xn[2], xn[3]));

    { // prefetch next tile's x
      int tn = (i + 1 < TPW) ? (t + 1) : t;
      const float* pn = x + (size_t)(tn * 16 + b) * 64 + 8 * h;
      xn[0] = *(const f32x4*)(pn);      xn[1] = *(const f32x4*)(pn + 4);
      xn[2] = *(const f32x4*)(pn + 32); xn[3] = *(const f32x4*)(pn + 36);
    }

    float rstd, nm;   // running LN stats of the PREVIOUS layer's gelu output

    // ---- layer 1: x -> W1 + b1 -> gelu; stats; pack UN-normalized ----
    {
      const uint8_t* wp = Wl + rowB;
      f32x4 acc[4];
      #pragma unroll
      for (int mt = 0; mt < 4; ++mt) {
        u32x4 w0 = *(const u32x4*)(wp + mt * 2048 + ((kOff     ) ^ swzW));
        u32x4 w1 = *(const u32x4*)(wp + mt * 2048 + ((kOff + 64) ^ swzW));
        int base = 8 * h + 4 * (mt & 1) + 32 * (mt >> 1);
        acc[mt] = *(const f32x4*)(biasL + base);
        acc[mt] = __builtin_amdgcn_mfma_f32_16x16x32_bf16(
            __builtin_bit_cast(bf16x8, w0), __builtin_bit_cast(bf16x8, bfr[0]), acc[mt], 0, 0, 0);
        acc[mt] = __builtin_amdgcn_mfma_f32_16x16x32_bf16(
            __builtin_bit_cast(bf16x8, w1), __builtin_bit_cast(bf16x8, bfr[1]), acc[mt], 0, 0, 0);
      }
      #pragma unroll
      for (int mt = 0; mt < 4; ++mt) acc[mt] = gelu4(acc[mt]);

      f32x4 vs = acc[0] + acc[1] + acc[2] + acc[3];
      f32x4 vq = acc[0]*acc[0] + acc[1]*acc[1] + acc[2]*acc[2] + acc[3]*acc[3];
      float s1 = (vs[0]+vs[1]) + (vs[2]+vs[3]);
      float s2 = (vq[0]+vq[1]) + (vq[2]+vq[3]);
      s1 += __shfl_xor(s1, 16); s2 += __shfl_xor(s2, 16);
      s1 += __shfl_xor(s1, 32); s2 += __shfl_xor(s2, 32);
      float mu  = s1 * (1.0f/64.0f);
      float var = __builtin_fmaf(s2, (1.0f/64.0f), -mu * mu);
      rstd = rsqrtf(var + 1e-5f);
      nm   = -mu * rstd;
      // pack raw gelu output: LN applied post-matmul next layer
      bfr[0] = __builtin_bit_cast(u32x4, mk_bf8(acc[0], acc[1]));
      bfr[1] = __builtin_bit_cast(u32x4, mk_bf8(acc[2], acc[3]));
    }

    // ---- layers 2,3: MFMA on raw v, then correction acc*rstd + (nm*ws + b') ----
    #pragma unroll
    for (int L = 1; L < 3; ++L) {
      const uint8_t* wp = Wl + L * 8192 + rowB;
      f32x4 acc[4];
      #pragma unroll
      for (int mt = 0; mt < 4; ++mt) {
        u32x4 w0 = *(const u32x4*)(wp + mt * 2048 + ((kOff     ) ^ swzW));
        u32x4 w1 = *(const u32x4*)(wp + mt * 2048 + ((kOff + 64) ^ swzW));
        acc[mt] = __builtin_amdgcn_mfma_f32_16x16x32_bf16(
            __builtin_bit_cast(bf16x8, w0), __builtin_bit_cast(bf16x8, bfr[0]), zf, 0, 0, 0);
        acc[mt] = __builtin_amdgcn_mfma_f32_16x16x32_bf16(
            __builtin_bit_cast(bf16x8, w1), __builtin_bit_cast(bf16x8, bfr[1]), acc[mt], 0, 0, 0);
      }
      #pragma unroll
      for (int mt = 0; mt < 4; ++mt) {
        int base = 8 * h + 4 * (mt & 1) + 32 * (mt >> 1);
        f32x4 bb = *(const f32x4*)(biasL + (L    ) * 64 + base);   // b2'|b3'
        f32x4 ws = *(const f32x4*)(biasL + (L+2) * 64 + base);     // ws2|ws3
        f32x4 tv = ws * nm + bb;
        acc[mt] = acc[mt] * rstd + tv;
      }
      #pragma unroll
      for (int mt = 0; mt < 4; ++mt) acc[mt] = gelu4(acc[mt]);

      f32x4 vs = acc[0] + acc[1] + acc[2] + acc[3];
      f32x4 vq = acc[0]*acc[0] + acc[1]*acc[1] + acc[2]*acc[2] + acc[3]*acc[3];
      float s1 = (vs[0]+vs[1]) + (vs[2]+vs[3]);
      float s2 = (vq[0]+vq[1]) + (vq[2]+vq[3]);
      s1 += __shfl_xor(s1, 16); s2 += __shfl_xor(s2, 16);
      s1 += __shfl_xor(s1, 32); s2 += __shfl_xor(s2, 32);
      float mu  = s1 * (1.0f/64.0f);
      float var = __builtin_fmaf(s2, (1.0f/64.0f), -mu * mu);
      rstd = rsqrtf(var + 1e-5f);
      nm   = -mu * rstd;
      bfr[0] = __builtin_bit_cast(u32x4, mk_bf8(acc[0], acc[1]));
      bfr[1] = __builtin_bit_cast(u32x4, mk_bf8(acc[2], acc[3]));
    }

    // ---- projection on raw v3: ao = (Wo'v3)*rstd + (nm*wso + bo') ----
    f32x4 ao;
    {
      const uint8_t* wp = Wl + WO_OFF + rowB;
      u32x4 w0 = *(const u32x4*)(wp + ((kOff     ) ^ swzW));
      u32x4 w1 = *(const u32x4*)(wp + ((kOff + 64) ^ swzW));
      ao = __builtin_amdgcn_mfma_f32_16x16x32_bf16(
          __builtin_bit_cast(bf16x8, w0), __builtin_bit_cast(bf16x8, bfr[0]), zf, 0, 0, 0);
      ao = __builtin_amdgcn_mfma_f32_16x16x32_bf16(
          __builtin_bit_cast(bf16x8, w1), __builtin_bit_cast(bf16x8, bfr[1]), ao, 0, 0, 0);
      f32x4 tv = wsoInit * nm + aoInit;
      ao = ao * rstd + tv;
    }

    // gather 16x5 floats in per-wave LDS slot, store 320B coalesced
    #pragma unroll
    for (int r = 0; r < 4; ++r) {
      int v = 4 * h + r;
      if (v < VOCAB) myF[b * VOCAB + v] = ao[r];
    }
    float* dst = tmp + (size_t)t * 80;
    dst[lane] = myF[lane];
    if (lane < 16) dst[64 + lane] = myF[64 + lane];
  }
}

// symmetrize: out[b,i,j,:] = 0.5*(tmp[b,i,j,:] + tmp[b,j,i,:]), LDS tile transpose
__global__ __launch_bounds__(256)
void sym_kernel(const float* __restrict__ tmp, float* __restrict__ out)
{
  __shared__ float A[32][164];
  __shared__ float B[32][164];
  int bid = blockIdx.x;
  int bb = bid / 144, r2 = bid - bb * 144;
  int ti = r2 / 12,  tj = r2 - ti * 12;
  int i0 = ti * 32,  j0 = tj * 32;
  const size_t base = (size_t)bb * SDIM * SDIM;

  for (int idx = threadIdx.x; idx < 32 * 160; idx += 256) {
    int r = idx / 160, c = idx - r * 160;
    A[r][c] = tmp[(base + (size_t)(i0 + r) * SDIM + j0) * VOCAB + c];
    B[r][c] = tmp[(base + (size_t)(j0 + r) * SDIM + i0) * VOCAB + c];
  }
  __syncthreads();
  for (int idx = threadIdx.x; idx < 32 * 160; idx += 256) {
    int r = idx / 160, c = idx - r * 160;
    int jc = c / 5, v = c - jc * 5;
    out[(base + (size_t)(i0 + r) * SDIM + j0) * VOCAB + c] =
        0.5f * (A[r][c] + B[jc][r * 5 + v]);
  }
}

extern "C" void kernel_launch(void* const* d_in, const int* in_sizes, int n_in,
                              void* d_out, int out_size, void* d_ws, size_t ws_size,
                              hipStream_t stream)
{
  const float* x   = (const float*)d_in[0];
  const float* W1  = (const float*)d_in[1];
  const float* b1  = (const float*)d_in[2];
  const float* W2  = (const float*)d_in[3];
  const float* b2  = (const float*)d_in[4];
  const float* W3  = (const float*)d_in[5];
  const float* b3  = (const float*)d_in[6];
  const float* lng = (const float*)d_in[7];
  const float* lnb = (const float*)d_in[8];
  const float* Wo  = (const float*)d_in[9];
  const float* bo  = (const float*)d_in[10];

  float* tmp = (float*)d_ws;   // 23.6 MB scratch
  float* out = (float*)d_out;

  mlp_kernel<<<BLOCKS, 256, 0, stream>>>(x, W1, b1, W2, b2, W3, b3,
                                         lng, lnb, Wo, bo, tmp);
  sym_kernel<<<8 * 12 * 12, 256, 0, stream>>>(tmp, out);
}

// Round 9
// 170.922 us; speedup vs baseline: 1.0713x; 1.0713x over previous
//
#include <hip/hip_runtime.h>
#include <cstdint>
#include <cstddef>

typedef __attribute__((ext_vector_type(8))) __bf16   bf16x8;
typedef __attribute__((ext_vector_type(2))) __bf16   bf16x2;
typedef __attribute__((ext_vector_type(4))) float    f32x4;
typedef __attribute__((ext_vector_type(4))) uint32_t u32x4;

#define N_ROWS   1179648   // 8*384*384
#define N_TILES  73728     // N_ROWS/16
#define BLOCKS   1024      // 4 waves -> 4096 waves -> 9 pairs (18 tiles)/wave
#define PPW      9
#define SDIM     384
#define VOCAB    5

// LDS map (29952 B -> 5 blocks/CU):
// [0,24576) W1|W2'|W3' bf16 permuted+swizzled; [24576,26624) Wo'^T padded;
// [26624,27392) b1|b2'|b3' f32; [27392,29952) 4 waves x 640B out-gather
#define WO_OFF   24576
#define BIAS_OFF 26624
#define OUT_OFF  27392

// tanh-form GELU via exp2+rcp: gelu(x) ~= x / (1 + exp2(x*(c1+c2*x^2)))
// |err vs exact| <= ~4e-4 (threshold 7.75e-2)
__device__ __forceinline__ f32x4 gelu4(f32x4 x){
  f32x4 u = x * x;
  f32x4 w = u * (-0.10294456f) + (-2.3021255f);
  f32x4 z = x * w;
  f32x4 e;
  e[0] = __builtin_amdgcn_exp2f(z[0]);
  e[1] = __builtin_amdgcn_exp2f(z[1]);
  e[2] = __builtin_amdgcn_exp2f(z[2]);
  e[3] = __builtin_amdgcn_exp2f(z[3]);
  f32x4 d = e + 1.0f;
  f32x4 r;
  r[0] = __builtin_amdgcn_rcpf(d[0]);
  r[1] = __builtin_amdgcn_rcpf(d[1]);
  r[2] = __builtin_amdgcn_rcpf(d[2]);
  r[3] = __builtin_amdgcn_rcpf(d[3]);
  return x * r;
}

__device__ __forceinline__ bf16x8 mk_bf8(f32x4 a, f32x4 b){
  bf16x8 v;
  v[0]=(__bf16)a[0]; v[1]=(__bf16)a[1]; v[2]=(__bf16)a[2]; v[3]=(__bf16)a[3];
  v[4]=(__bf16)b[0]; v[5]=(__bf16)b[1]; v[6]=(__bf16)b[2]; v[7]=(__bf16)b[3];
  return v;
}

// W-row permutation: global row m -> LDS A-row rho, so acc[mt][r] of lane (h,b)
// is feature 8h + r + 4*(mt&1) + 32*(mt>>1) -> next B frag is pure register repack.
__device__ __forceinline__ int perm_rho(int m){
  return (m & 0x23) | ((m & 4) << 2) | ((m & 0x18) >> 1);
}

__global__ __launch_bounds__(256)
void mlp_kernel(const float* __restrict__ x,
                const float* __restrict__ W1, const float* __restrict__ b1,
                const float* __restrict__ W2, const float* __restrict__ b2,
                const float* __restrict__ W3, const float* __restrict__ b3,
                const float* __restrict__ lng, const float* __restrict__ lnb,
                const float* __restrict__ Wo,  const float* __restrict__ bo,
                float* __restrict__ tmp)
{
  __shared__ __align__(16) uint8_t Wl[29952];

  const int tid = threadIdx.x;

  // ---- stage weights with LN-affine folding ----
  // W1 raw; W2',W3',Wo' have column k scaled by lng[k] (they consume LN outputs).
  {
    int m = tid & 63, g = tid >> 6;
    int rho = perm_rho(m);
    uint8_t* wrow = Wl + rho * 128;
    int swz = (rho & 7) << 4;
    #pragma unroll 1
    for (int idx = g; idx < 96; idx += 4) {   // idx = L*32 + kp
      int L = idx >> 5, kp = idx & 31;
      const float* W = (L == 0) ? W1 : ((L == 1) ? W2 : W3);
      float g0 = (L == 0) ? 1.0f : lng[2 * kp];
      float g1 = (L == 0) ? 1.0f : lng[2 * kp + 1];
      float lo = W[(2 * kp    ) * 64 + m] * g0;
      float hi = W[(2 * kp + 1) * 64 + m] * g1;
      bf16x2 p = { (__bf16)lo, (__bf16)hi };
      *(uint32_t*)(wrow + L * 8192 + ((4 * kp) ^ swz)) = __builtin_bit_cast(uint32_t, p);
    }
    int mm = tid & 15;
    #pragma unroll 1
    for (int kp = tid >> 4; kp < 32; kp += 16) {    // Wo' rows 0..15 (>=5 zero)
      float g0 = lng[2 * kp], g1 = lng[2 * kp + 1];
      float lo = (mm < VOCAB) ? Wo[(2 * kp    ) * VOCAB + mm] * g0 : 0.0f;
      float hi = (mm < VOCAB) ? Wo[(2 * kp + 1) * VOCAB + mm] * g1 : 0.0f;
      bf16x2 p = { (__bf16)lo, (__bf16)hi };
      *(uint32_t*)(Wl + WO_OFF + mm * 128 + ((4 * kp) ^ ((mm & 7) << 4))) =
          __builtin_bit_cast(uint32_t, p);
    }
    // b1 raw; b2' = b2 + W2^T.lnb ; b3' = b3 + W3^T.lnb
    if (tid < 128) {
      int m2 = tid & 63;
      const float* W = (tid < 64) ? W2 : W3;
      float d = (tid < 64) ? b2[m2] : b3[m2];
      #pragma unroll 4
      for (int k = 0; k < 64; ++k) d = __builtin_fmaf(W[k * 64 + m2], lnb[k], d);
      *(float*)(Wl + BIAS_OFF + (64 + tid) * 4) = d;     // slots [64,192)
    } else if (tid < 192) {
      *(float*)(Wl + BIAS_OFF + (tid - 128) * 4) = b1[tid - 128];
    }
  }
  __syncthreads();

  const int wav  = tid >> 6, lane = tid & 63;
  const int h    = lane >> 4;
  const int b    = lane & 15;
  const int swzW = (b & 7) << 4;
  const int rowB = b * 128;
  const int kOff = 16 * h;
  const float* biasL = (const float*)(Wl + BIAS_OFF);
  float* myF = (float*)(Wl + OUT_OFF) + wav * 160;

  // bo' = bo + Wo^T.lnb (per-lane, prologue)
  f32x4 aoInit;
  #pragma unroll
  for (int r = 0; r < 4; ++r) {
    int v = 4 * h + r;
    aoInit[r] = (v < VOCAB) ? bo[v] : 0.0f;
  }
  #pragma unroll 4
  for (int k = 0; k < 64; ++k) {
    float lb = lnb[k];
    #pragma unroll
    for (int r = 0; r < 4; ++r) {
      int v = 4 * h + r;
      if (v < VOCAB) aoInit[r] = __builtin_fmaf(lb, Wo[k * VOCAB + v], aoInit[r]);
    }
  }

  const int gw = blockIdx.x * 4 + wav;   // 0..4095
  int t = gw * PPW * 2;                  // even base tile of the pair

  // prime prefetch of first pair (tiles t, t+1): 32 contiguous rows
  f32x4 xn[8];
  {
    const float* p0 = x + (size_t)(t * 16 + b) * 64 + 8 * h;
    xn[0] = *(const f32x4*)(p0);      xn[1] = *(const f32x4*)(p0 + 4);
    xn[2] = *(const f32x4*)(p0 + 32); xn[3] = *(const f32x4*)(p0 + 36);
    const float* p1 = p0 + 1024;
    xn[4] = *(const f32x4*)(p1);      xn[5] = *(const f32x4*)(p1 + 4);
    xn[6] = *(const f32x4*)(p1 + 32); xn[7] = *(const f32x4*)(p1 + 36);
  }

  #pragma unroll 1
  for (int i = 0; i < PPW; ++i, t += 2) {
    u32x4 bfA[2], bfB[2];
    bfA[0] = __builtin_bit_cast(u32x4, mk_bf8(xn[0], xn[1]));
    bfA[1] = __builtin_bit_cast(u32x4, mk_bf8(xn[2], xn[3]));
    bfB[0] = __builtin_bit_cast(u32x4, mk_bf8(xn[4], xn[5]));
    bfB[1] = __builtin_bit_cast(u32x4, mk_bf8(xn[6], xn[7]));

    { // prefetch next pair (hidden under this pair's compute)
      int tn = (i + 1 < PPW) ? (t + 2) : t;
      const float* p0 = x + (size_t)(tn * 16 + b) * 64 + 8 * h;
      xn[0] = *(const f32x4*)(p0);      xn[1] = *(const f32x4*)(p0 + 4);
      xn[2] = *(const f32x4*)(p0 + 32); xn[3] = *(const f32x4*)(p0 + 36);
      const float* p1 = p0 + 1024;
      xn[4] = *(const f32x4*)(p1);      xn[5] = *(const f32x4*)(p1 + 4);
      xn[6] = *(const f32x4*)(p1 + 32); xn[7] = *(const f32x4*)(p1 + 36);
    }

    // ---- three (Linear -> gelu -> LN) blocks, two independent chains ----
    #pragma unroll
    for (int L = 0; L < 3; ++L) {
      const uint8_t* wp = Wl + L * 8192 + rowB;
      f32x4 accA[4], accB[4];
      #pragma unroll
      for (int mt = 0; mt < 4; ++mt) {
        u32x4 w0 = *(const u32x4*)(wp + mt * 2048 + ((kOff     ) ^ swzW));
        u32x4 w1 = *(const u32x4*)(wp + mt * 2048 + ((kOff + 64) ^ swzW));
        int base = 8 * h + 4 * (mt & 1) + 32 * (mt >> 1);
        f32x4 bini = *(const f32x4*)(biasL + L * 64 + base);
        accA[mt] = __builtin_amdgcn_mfma_f32_16x16x32_bf16(
            __builtin_bit_cast(bf16x8, w0), __builtin_bit_cast(bf16x8, bfA[0]), bini, 0, 0, 0);
        accA[mt] = __builtin_amdgcn_mfma_f32_16x16x32_bf16(
            __builtin_bit_cast(bf16x8, w1), __builtin_bit_cast(bf16x8, bfA[1]), accA[mt], 0, 0, 0);
        accB[mt] = __builtin_amdgcn_mfma_f32_16x16x32_bf16(
            __builtin_bit_cast(bf16x8, w0), __builtin_bit_cast(bf16x8, bfB[0]), bini, 0, 0, 0);
        accB[mt] = __builtin_amdgcn_mfma_f32_16x16x32_bf16(
            __builtin_bit_cast(bf16x8, w1), __builtin_bit_cast(bf16x8, bfB[1]), accB[mt], 0, 0, 0);
      }

      #pragma unroll
      for (int mt = 0; mt < 4; ++mt) { accA[mt] = gelu4(accA[mt]); accB[mt] = gelu4(accB[mt]); }

      // LN stats: two independent shfl chains (overlap each other's latency)
      f32x4 vsA = accA[0] + accA[1] + accA[2] + accA[3];
      f32x4 vsB = accB[0] + accB[1] + accB[2] + accB[3];
      f32x4 vqA = accA[0]*accA[0] + accA[1]*accA[1] + accA[2]*accA[2] + accA[3]*accA[3];
      f32x4 vqB = accB[0]*accB[0] + accB[1]*accB[1] + accB[2]*accB[2] + accB[3]*accB[3];
      float s1A = (vsA[0]+vsA[1]) + (vsA[2]+vsA[3]);
      float s2A = (vqA[0]+vqA[1]) + (vqA[2]+vqA[3]);
      float s1B = (vsB[0]+vsB[1]) + (vsB[2]+vsB[3]);
      float s2B = (vqB[0]+vqB[1]) + (vqB[2]+vqB[3]);
      s1A += __shfl_xor(s1A, 16); s2A += __shfl_xor(s2A, 16);
      s1B += __shfl_xor(s1B, 16); s2B += __shfl_xor(s2B, 16);
      s1A += __shfl_xor(s1A, 32); s2A += __shfl_xor(s2A, 32);
      s1B += __shfl_xor(s1B, 32); s2B += __shfl_xor(s2B, 32);
      float muA = s1A * (1.0f/64.0f), muB = s1B * (1.0f/64.0f);
      float vrA = __builtin_fmaf(s2A, (1.0f/64.0f), -muA*muA);
      float vrB = __builtin_fmaf(s2B, (1.0f/64.0f), -muB*muB);
      float rsA = rsqrtf(vrA + 1e-5f), rsB = rsqrtf(vrB + 1e-5f);
      float nmA = -muA * rsA,          nmB = -muB * rsB;

      // pure normalize (affine folded into next weights), register repack
      f32x4 nA0 = accA[0] * rsA + nmA, nA1 = accA[1] * rsA + nmA;
      f32x4 nA2 = accA[2] * rsA + nmA, nA3 = accA[3] * rsA + nmA;
      f32x4 nB0 = accB[0] * rsB + nmB, nB1 = accB[1] * rsB + nmB;
      f32x4 nB2 = accB[2] * rsB + nmB, nB3 = accB[3] * rsB + nmB;
      bfA[0] = __builtin_bit_cast(u32x4, mk_bf8(nA0, nA1));
      bfA[1] = __builtin_bit_cast(u32x4, mk_bf8(nA2, nA3));
      bfB[0] = __builtin_bit_cast(u32x4, mk_bf8(nB0, nB1));
      bfB[1] = __builtin_bit_cast(u32x4, mk_bf8(nB2, nB3));
    }

    // ---- output projection (shared Wo' frags), C-init = bo' ----
    f32x4 aoA, aoB;
    {
      const uint8_t* wp = Wl + WO_OFF + rowB;
      u32x4 w0 = *(const u32x4*)(wp + ((kOff     ) ^ swzW));
      u32x4 w1 = *(const u32x4*)(wp + ((kOff + 64) ^ swzW));
      aoA = __builtin_amdgcn_mfma_f32_16x16x32_bf16(
          __builtin_bit_cast(bf16x8, w0), __builtin_bit_cast(bf16x8, bfA[0]), aoInit, 0, 0, 0);
      aoA = __builtin_amdgcn_mfma_f32_16x16x32_bf16(
          __builtin_bit_cast(bf16x8, w1), __builtin_bit_cast(bf16x8, bfA[1]), aoA, 0, 0, 0);
      aoB = __builtin_amdgcn_mfma_f32_16x16x32_bf16(
          __builtin_bit_cast(bf16x8, w0), __builtin_bit_cast(bf16x8, bfB[0]), aoInit, 0, 0, 0);
      aoB = __builtin_amdgcn_mfma_f32_16x16x32_bf16(
          __builtin_bit_cast(bf16x8, w1), __builtin_bit_cast(bf16x8, bfB[1]), aoB, 0, 0, 0);
    }

    // gather 2x16x5 floats in per-wave LDS slot, store 640B coalesced
    #pragma unroll
    for (int r = 0; r < 4; ++r) {
      int v = 4 * h + r;
      if (v < VOCAB) {
        myF[      b * VOCAB + v] = aoA[r];
        myF[80  + b * VOCAB + v] = aoB[r];
      }
    }
    float* dst = tmp + (size_t)t * 80;
    dst[lane]      = myF[lane];
    dst[64 + lane] = myF[64 + lane];
    if (lane < 32) dst[128 + lane] = myF[128 + lane];
  }
}

// symmetrize: out[b,i,j,:] = 0.5*(tmp[b,i,j,:] + tmp[b,j,i,:]), LDS tile transpose
__global__ __launch_bounds__(256)
void sym_kernel(const float* __restrict__ tmp, float* __restrict__ out)
{
  __shared__ float A[32][164];
  __shared__ float B[32][164];
  int bid = blockIdx.x;
  int bb = bid / 144, r2 = bid - bb * 144;
  int ti = r2 / 12,  tj = r2 - ti * 12;
  int i0 = ti * 32,  j0 = tj * 32;
  const size_t base = (size_t)bb * SDIM * SDIM;

  for (int idx = threadIdx.x; idx < 32 * 160; idx += 256) {
    int r = idx / 160, c = idx - r * 160;
    A[r][c] = tmp[(base + (size_t)(i0 + r) * SDIM + j0) * VOCAB + c];
    B[r][c] = tmp[(base + (size_t)(j0 + r) * SDIM + i0) * VOCAB + c];
  }
  __syncthreads();
  for (int idx = threadIdx.x; idx < 32 * 160; idx += 256) {
    int r = idx / 160, c = idx - r * 160;
    int jc = c / 5, v = c - jc * 5;
    out[(base + (size_t)(i0 + r) * SDIM + j0) * VOCAB + c] =
        0.5f * (A[r][c] + B[jc][r * 5 + v]);
  }
}

extern "C" void kernel_launch(void* const* d_in, const int* in_sizes, int n_in,
                              void* d_out, int out_size, void* d_ws, size_t ws_size,
                              hipStream_t stream)
{
  const float* x   = (const float*)d_in[0];
  const float* W1  = (const float*)d_in[1];
  const float* b1  = (const float*)d_in[2];
  const float* W2  = (const float*)d_in[3];
  const float* b2  = (const float*)d_in[4];
  const float* W3  = (const float*)d_in[5];
  const float* b3  = (const float*)d_in[6];
  const float* lng = (const float*)d_in[7];
  const float* lnb = (const float*)d_in[8];
  const float* Wo  = (const float*)d_in[9];
  const float* bo  = (const float*)d_in[10];

  float* tmp = (float*)d_ws;   // 23.6 MB scratch
  float* out = (float*)d_out;

  mlp_kernel<<<BLOCKS, 256, 0, stream>>>(x, W1, b1, W2, b2, W3, b3,
                                         lng, lnb, Wo, bo, tmp);
  sym_kernel<<<8 * 12 * 12, 256, 0, stream>>>(tmp, out);
}

// Round 10
// 167.749 us; speedup vs baseline: 1.0916x; 1.0189x over previous
//
#include <hip/hip_runtime.h>
#include <cstdint>
#include <cstddef>

typedef __attribute__((ext_vector_type(8))) __bf16   bf16x8;
typedef __attribute__((ext_vector_type(2))) __bf16   bf16x2;
typedef __attribute__((ext_vector_type(4))) float    f32x4;
typedef __attribute__((ext_vector_type(4))) uint32_t u32x4;

#define N_ROWS   1179648   // 8*384*384
#define N_TILES  73728     // N_ROWS/16
#define BLOCKS   2048      // 4 waves -> 8192 waves -> 9 tiles/wave
#define TPW      9
#define SDIM     384
#define VOCAB    5

// LDS map (28672 B): [0,24576) W1|W2'|W3' bf16 permuted+swizzled;
// [24576,26624) Wo'^T padded; [26624,27392) b1|b2'|b3' f32;
// [27392,28672) 4 waves x 320B out-gather
#define WO_OFF   24576
#define BIAS_OFF 26624
#define OUT_OFF  27392

// tanh-form GELU via exp2+rcp: gelu(x) ~= x / (1 + exp2(x*(c1+c2*x^2)))
// |err vs exact| <= ~4e-4 (threshold 7.75e-2)
__device__ __forceinline__ f32x4 gelu4(f32x4 x){
  f32x4 u = x * x;
  f32x4 w = u * (-0.10294456f) + (-2.3021255f);
  f32x4 z = x * w;
  f32x4 e;
  e[0] = __builtin_amdgcn_exp2f(z[0]);
  e[1] = __builtin_amdgcn_exp2f(z[1]);
  e[2] = __builtin_amdgcn_exp2f(z[2]);
  e[3] = __builtin_amdgcn_exp2f(z[3]);
  f32x4 d = e + 1.0f;
  f32x4 r;
  r[0] = __builtin_amdgcn_rcpf(d[0]);
  r[1] = __builtin_amdgcn_rcpf(d[1]);
  r[2] = __builtin_amdgcn_rcpf(d[2]);
  r[3] = __builtin_amdgcn_rcpf(d[3]);
  return x * r;
}

__device__ __forceinline__ bf16x8 mk_bf8(f32x4 a, f32x4 b){
  bf16x8 v;
  v[0]=(__bf16)a[0]; v[1]=(__bf16)a[1]; v[2]=(__bf16)a[2]; v[3]=(__bf16)a[3];
  v[4]=(__bf16)b[0]; v[5]=(__bf16)b[1]; v[6]=(__bf16)b[2]; v[7]=(__bf16)b[3];
  return v;
}

// W-row permutation: global row m -> LDS A-row rho, so acc[mt][r] of lane (h,b)
// is feature 8h + r + 4*(mt&1) + 32*(mt>>1) -> next B frag is pure register repack.
__device__ __forceinline__ int perm_rho(int m){
  return (m & 0x23) | ((m & 4) << 2) | ((m & 0x18) >> 1);
}

// (256,3): target 3 waves/SIMD (<=170 total regs). R7's (256,4)=128 caused heavy
// accvgpr churn; unclamped settles ~190-260 total -> only 2 waves/SIMD.
__global__ __launch_bounds__(256, 3)
void mlp_kernel(const float* __restrict__ x,
                const float* __restrict__ W1, const float* __restrict__ b1,
                const float* __restrict__ W2, const float* __restrict__ b2,
                const float* __restrict__ W3, const float* __restrict__ b3,
                const float* __restrict__ lng, const float* __restrict__ lnb,
                const float* __restrict__ Wo,  const float* __restrict__ bo,
                float* __restrict__ tmp)
{
  __shared__ __align__(16) uint8_t Wl[28672];

  const int tid = threadIdx.x;

  // ---- stage weights with LN-affine folding ----
  // W1 raw; W2',W3',Wo' have column k scaled by lng[k] (they consume LN outputs).
  {
    int m = tid & 63, g = tid >> 6;
    int rho = perm_rho(m);
    uint8_t* wrow = Wl + rho * 128;
    int swz = (rho & 7) << 4;
    #pragma unroll 1
    for (int idx = g; idx < 96; idx += 4) {   // idx = L*32 + kp
      int L = idx >> 5, kp = idx & 31;
      const float* W = (L == 0) ? W1 : ((L == 1) ? W2 : W3);
      float g0 = (L == 0) ? 1.0f : lng[2 * kp];
      float g1 = (L == 0) ? 1.0f : lng[2 * kp + 1];
      float lo = W[(2 * kp    ) * 64 + m] * g0;
      float hi = W[(2 * kp + 1) * 64 + m] * g1;
      bf16x2 p = { (__bf16)lo, (__bf16)hi };
      *(uint32_t*)(wrow + L * 8192 + ((4 * kp) ^ swz)) = __builtin_bit_cast(uint32_t, p);
    }
    int mm = tid & 15;
    #pragma unroll 1
    for (int kp = tid >> 4; kp < 32; kp += 16) {    // Wo' rows 0..15 (>=5 zero)
      float g0 = lng[2 * kp], g1 = lng[2 * kp + 1];
      float lo = (mm < VOCAB) ? Wo[(2 * kp    ) * VOCAB + mm] * g0 : 0.0f;
      float hi = (mm < VOCAB) ? Wo[(2 * kp + 1) * VOCAB + mm] * g1 : 0.0f;
      bf16x2 p = { (__bf16)lo, (__bf16)hi };
      *(uint32_t*)(Wl + WO_OFF + mm * 128 + ((4 * kp) ^ ((mm & 7) << 4))) =
          __builtin_bit_cast(uint32_t, p);
    }
    // b1 raw; b2' = b2 + W2^T.lnb ; b3' = b3 + W3^T.lnb
    if (tid < 128) {
      int m2 = tid & 63;
      const float* W = (tid < 64) ? W2 : W3;
      float d = (tid < 64) ? b2[m2] : b3[m2];
      #pragma unroll 4
      for (int k = 0; k < 64; ++k) d = __builtin_fmaf(W[k * 64 + m2], lnb[k], d);
      *(float*)(Wl + BIAS_OFF + (64 + tid) * 4) = d;     // slots [64,192)
    } else if (tid < 192) {
      *(float*)(Wl + BIAS_OFF + (tid - 128) * 4) = b1[tid - 128];
    }
  }
  __syncthreads();

  const int wav  = tid >> 6, lane = tid & 63;
  const int h    = lane >> 4;
  const int b    = lane & 15;
  const int swzW = (b & 7) << 4;
  const int rowB = b * 128;
  const int kOff = 16 * h;
  const float* biasL = (const float*)(Wl + BIAS_OFF);
  float* myF = (float*)(Wl + OUT_OFF) + wav * 80;

  // bo' = bo + Wo^T.lnb (per-lane, prologue, off hot path)
  f32x4 aoInit;
  #pragma unroll
  for (int r = 0; r < 4; ++r) {
    int v = 4 * h + r;
    aoInit[r] = (v < VOCAB) ? bo[v] : 0.0f;
  }
  #pragma unroll 4
  for (int k = 0; k < 64; ++k) {
    float lb = lnb[k];
    #pragma unroll
    for (int r = 0; r < 4; ++r) {
      int v = 4 * h + r;
      if (v < VOCAB) aoInit[r] = __builtin_fmaf(lb, Wo[k * VOCAB + v], aoInit[r]);
    }
  }

  const int gw = blockIdx.x * 4 + wav;   // 0..8191
  int t = gw * TPW;

  f32x4 xn[4];
  {
    const float* px = x + (size_t)(t * 16 + b) * 64 + 8 * h;
    xn[0] = *(const f32x4*)(px);      xn[1] = *(const f32x4*)(px + 4);
    xn[2] = *(const f32x4*)(px + 32); xn[3] = *(const f32x4*)(px + 36);
  }

  #pragma unroll 1
  for (int i = 0; i < TPW; ++i, ++t) {
    u32x4 bfr[2];
    bfr[0] = __builtin_bit_cast(u32x4, mk_bf8(xn[0], xn[1]));
    bfr[1] = __builtin_bit_cast(u32x4, mk_bf8(xn[2], xn[3]));

    { // prefetch next tile's x (hidden under this tile's compute)
      int tn = (i + 1 < TPW) ? (t + 1) : t;
      const float* pn = x + (size_t)(tn * 16 + b) * 64 + 8 * h;
      xn[0] = *(const f32x4*)(pn);      xn[1] = *(const f32x4*)(pn + 4);
      xn[2] = *(const f32x4*)(pn + 32); xn[3] = *(const f32x4*)(pn + 36);
    }

    // ---- three (Linear -> gelu -> LN) blocks, zero inter-layer LDS ----
    #pragma unroll
    for (int L = 0; L < 3; ++L) {
      const uint8_t* wp = Wl + L * 8192 + rowB;
      f32x4 acc[4];
      #pragma unroll
      for (int mt = 0; mt < 4; ++mt) {
        u32x4 w0 = *(const u32x4*)(wp + mt * 2048 + ((kOff     ) ^ swzW));
        u32x4 w1 = *(const u32x4*)(wp + mt * 2048 + ((kOff + 64) ^ swzW));
        int base = 8 * h + 4 * (mt & 1) + 32 * (mt >> 1);
        acc[mt] = *(const f32x4*)(biasL + L * 64 + base);
        acc[mt] = __builtin_amdgcn_mfma_f32_16x16x32_bf16(
            __builtin_bit_cast(bf16x8, w0), __builtin_bit_cast(bf16x8, bfr[0]), acc[mt], 0, 0, 0);
        acc[mt] = __builtin_amdgcn_mfma_f32_16x16x32_bf16(
            __builtin_bit_cast(bf16x8, w1), __builtin_bit_cast(bf16x8, bfr[1]), acc[mt], 0, 0, 0);
      }

      #pragma unroll
      for (int mt = 0; mt < 4; ++mt) acc[mt] = gelu4(acc[mt]);

      // LayerNorm stats over row b (lanes b, b+16, b+32, b+48)
      f32x4 vs = acc[0] + acc[1] + acc[2] + acc[3];
      f32x4 vq = acc[0]*acc[0] + acc[1]*acc[1] + acc[2]*acc[2] + acc[3]*acc[3];
      float s1 = (vs[0]+vs[1]) + (vs[2]+vs[3]);
      float s2 = (vq[0]+vq[1]) + (vq[2]+vq[3]);
      s1 += __shfl_xor(s1, 16); s2 += __shfl_xor(s2, 16);
      s1 += __shfl_xor(s1, 32); s2 += __shfl_xor(s2, 32);
      float mu   = s1 * (1.0f/64.0f);
      float var  = __builtin_fmaf(s2, (1.0f/64.0f), -mu * mu);
      float rstd = rsqrtf(var + 1e-5f);
      float nm   = -mu * rstd;

      // pure normalize (affine folded into next weights), register repack
      f32x4 n0 = acc[0] * rstd + nm;
      f32x4 n1 = acc[1] * rstd + nm;
      f32x4 n2 = acc[2] * rstd + nm;
      f32x4 n3 = acc[3] * rstd + nm;
      bfr[0] = __builtin_bit_cast(u32x4, mk_bf8(n0, n1));
      bfr[1] = __builtin_bit_cast(u32x4, mk_bf8(n2, n3));
    }

    // ---- output projection out^T = Wo'^T . n3^T, C-init = bo' ----
    f32x4 ao;
    {
      const uint8_t* wp = Wl + WO_OFF + rowB;
      u32x4 w0 = *(const u32x4*)(wp + ((kOff     ) ^ swzW));
      u32x4 w1 = *(const u32x4*)(wp + ((kOff + 64) ^ swzW));
      ao = __builtin_amdgcn_mfma_f32_16x16x32_bf16(
          __builtin_bit_cast(bf16x8, w0), __builtin_bit_cast(bf16x8, bfr[0]), aoInit, 0, 0, 0);
      ao = __builtin_amdgcn_mfma_f32_16x16x32_bf16(
          __builtin_bit_cast(bf16x8, w1), __builtin_bit_cast(bf16x8, bfr[1]), ao, 0, 0, 0);
    }

    // gather 16x5 floats in per-wave LDS slot, store 320B coalesced
    #pragma unroll
    for (int r = 0; r < 4; ++r) {
      int v = 4 * h + r;
      if (v < VOCAB) myF[b * VOCAB + v] = ao[r];
    }
    float* dst = tmp + (size_t)t * 80;
    dst[lane] = myF[lane];
    if (lane < 16) dst[64 + lane] = myF[64 + lane];
  }
}

// symmetrize: out[b,i,j,:] = 0.5*(tmp[b,i,j,:] + tmp[b,j,i,:]), LDS tile transpose
__global__ __launch_bounds__(256)
void sym_kernel(const float* __restrict__ tmp, float* __restrict__ out)
{
  __shared__ float A[32][164];
  __shared__ float B[32][164];
  int bid = blockIdx.x;
  int bb = bid / 144, r2 = bid - bb * 144;
  int ti = r2 / 12,  tj = r2 - ti * 12;
  int i0 = ti * 32,  j0 = tj * 32;
  const size_t base = (size_t)bb * SDIM * SDIM;

  for (int idx = threadIdx.x; idx < 32 * 160; idx += 256) {
    int r = idx / 160, c = idx - r * 160;
    A[r][c] = tmp[(base + (size_t)(i0 + r) * SDIM + j0) * VOCAB + c];
    B[r][c] = tmp[(base + (size_t)(j0 + r) * SDIM + i0) * VOCAB + c];
  }
  __syncthreads();
  for (int idx = threadIdx.x; idx < 32 * 160; idx += 256) {
    int r = idx / 160, c = idx - r * 160;
    int jc = c / 5, v = c - jc * 5;
    out[(base + (size_t)(i0 + r) * SDIM + j0) * VOCAB + c] =
        0.5f * (A[r][c] + B[jc][r * 5 + v]);
  }
}

extern "C" void kernel_launch(void* const* d_in, const int* in_sizes, int n_in,
                              void* d_out, int out_size, void* d_ws, size_t ws_size,
                              hipStream_t stream)
{
  const float* x   = (const float*)d_in[0];
  const float* W1  = (const float*)d_in[1];
  const float* b1  = (const float*)d_in[2];
  const float* W2  = (const float*)d_in[3];
  const float* b2  = (const float*)d_in[4];
  const float* W3  = (const float*)d_in[5];
  const float* b3  = (const float*)d_in[6];
  const float* lng = (const float*)d_in[7];
  const float* lnb = (const float*)d_in[8];
  const float* Wo  = (const float*)d_in[9];
  const float* bo  = (const float*)d_in[10];

  float* tmp = (float*)d_ws;   // 23.6 MB scratch
  float* out = (float*)d_out;

  mlp_kernel<<<BLOCKS, 256, 0, stream>>>(x, W1, b1, W2, b2, W3, b3,
                                         lng, lnb, Wo, bo, tmp);
  sym_kernel<<<8 * 12 * 12, 256, 0, stream>>>(tmp, out);
}